// Round 1
// baseline (3535.047 us; speedup 1.0000x reference)
//
#include <hip/hip_runtime.h>

// SparseMultiHeadAttention: B=4 S=2048 D=1024 H=16 DK=64 WINDOW=256 GLOBAL=16
// Round 0: correctness-anchor, all-fp32 vector implementation.
//   k1-3: gemm_f32 projections q/k/v -> Q,K,V in (B,H,S,DK) layout (d_ws)
//   k4  : flash-style banded attention -> AO in (B,S,D) layout (d_ws)
//   k5  : gemm_f32 out-proj AO @ wo + bo -> d_out
// ws usage: 4 * 32 MiB = 128 MiB.

#define B_   4
#define S_   2048
#define D_   1024
#define H_   16
#define DK_  64
#define WIN_ 256
#define GLB_ 16

// ---------------------------------------------------------------------------
// GEMM: C = A(8192x1024) @ W(1024x1024) + bias
// mode 0: C row-major (m,n)
// mode 1: C head layout: m=(b,s), n=(h,dk) -> C[((b*H+h)*S+s)*DK+dk]
// Tiles: BM=128, BN=128, BK=16; 256 threads; 8x8 per thread.
// ---------------------------------------------------------------------------
#define BM 128
#define BN 128
#define BK 16

__global__ __launch_bounds__(256, 2) void gemm_f32(
    const float* __restrict__ A, const float* __restrict__ W,
    const float* __restrict__ bias, float* __restrict__ C, int mode)
{
  __shared__ float As[BK][BM + 4];   // transposed A tile: As[k][m]
  __shared__ float Bs[BK][BN + 4];   // Bs[k][n]
  const int tid = threadIdx.x;
  const int bm = blockIdx.y * BM;
  const int bn = blockIdx.x * BN;
  const int tx = tid & 15;   // 16 col-groups of 8
  const int ty = tid >> 4;   // 16 row-groups of 8
  const int K = 1024, N = 1024;

  float acc[8][8];
#pragma unroll
  for (int i = 0; i < 8; ++i)
#pragma unroll
    for (int j = 0; j < 8; ++j) acc[i][j] = 0.f;

  const int arow = tid >> 2;        // 0..63
  const int acol = (tid & 3) * 4;   // 0,4,8,12
  const int brow = tid >> 5;        // 0..7
  const int bcol = (tid & 31) * 4;  // 0..124

  for (int k0 = 0; k0 < K; k0 += BK) {
    // global loads issued before the barrier to overlap with the wait
    float4 a0 = *(const float4*)(A + (size_t)(bm + arow) * K + k0 + acol);
    float4 a1 = *(const float4*)(A + (size_t)(bm + arow + 64) * K + k0 + acol);
    float4 b0 = *(const float4*)(W + (size_t)(k0 + brow) * N + bn + bcol);
    float4 b1 = *(const float4*)(W + (size_t)(k0 + brow + 8) * N + bn + bcol);
    __syncthreads();   // previous iteration's readers done
    As[acol + 0][arow] = a0.x; As[acol + 1][arow] = a0.y;
    As[acol + 2][arow] = a0.z; As[acol + 3][arow] = a0.w;
    As[acol + 0][arow + 64] = a1.x; As[acol + 1][arow + 64] = a1.y;
    As[acol + 2][arow + 64] = a1.z; As[acol + 3][arow + 64] = a1.w;
    *(float4*)&Bs[brow][bcol]     = b0;
    *(float4*)&Bs[brow + 8][bcol] = b1;
    __syncthreads();
#pragma unroll
    for (int kk = 0; kk < BK; ++kk) {
      float a[8], b[8];
      float4 t;
      t = *(float4*)&As[kk][ty * 8];     a[0]=t.x; a[1]=t.y; a[2]=t.z; a[3]=t.w;
      t = *(float4*)&As[kk][ty * 8 + 4]; a[4]=t.x; a[5]=t.y; a[6]=t.z; a[7]=t.w;
      t = *(float4*)&Bs[kk][tx * 8];     b[0]=t.x; b[1]=t.y; b[2]=t.z; b[3]=t.w;
      t = *(float4*)&Bs[kk][tx * 8 + 4]; b[4]=t.x; b[5]=t.y; b[6]=t.z; b[7]=t.w;
#pragma unroll
      for (int i = 0; i < 8; ++i)
#pragma unroll
        for (int j = 0; j < 8; ++j)
          acc[i][j] = fmaf(a[i], b[j], acc[i][j]);
    }
  }

  const float4 bias0 = *(const float4*)(bias + bn + tx * 8);
  const float4 bias1 = *(const float4*)(bias + bn + tx * 8 + 4);
  if (mode == 0) {
#pragma unroll
    for (int i = 0; i < 8; ++i) {
      const int m = bm + ty * 8 + i;
      float* dst = C + (size_t)m * 1024 + bn + tx * 8;
      float4 o0 = make_float4(acc[i][0] + bias0.x, acc[i][1] + bias0.y,
                              acc[i][2] + bias0.z, acc[i][3] + bias0.w);
      float4 o1 = make_float4(acc[i][4] + bias1.x, acc[i][5] + bias1.y,
                              acc[i][6] + bias1.z, acc[i][7] + bias1.w);
      *(float4*)dst = o0; *(float4*)(dst + 4) = o1;
    }
  } else {
    const int ncol = bn + tx * 8;       // 8 cols never cross a head boundary
    const int h  = ncol >> 6;
    const int dk = ncol & 63;
#pragma unroll
    for (int i = 0; i < 8; ++i) {
      const int m = bm + ty * 8 + i;
      const int bb = m >> 11;           // S_=2048
      const int s  = m & 2047;
      float* dst = C + ((size_t)(bb * H_ + h) * S_ + s) * DK_ + dk;
      float4 o0 = make_float4(acc[i][0] + bias0.x, acc[i][1] + bias0.y,
                              acc[i][2] + bias0.z, acc[i][3] + bias0.w);
      float4 o1 = make_float4(acc[i][4] + bias1.x, acc[i][5] + bias1.y,
                              acc[i][6] + bias1.z, acc[i][7] + bias1.w);
      *(float4*)dst = o0; *(float4*)(dst + 4) = o1;
    }
  }
}

// ---------------------------------------------------------------------------
// Banded attention, flash-style, fp32.
// Block = 256 threads, handles one (b, h, 32-row Q tile).
// Key tiles visited: tile 0 (global keys) + [ (i0-WIN)>>5 , (i0>>5)+8 ];
// the i0==0 tile (which contains the global query rows i<16) visits all 64.
// Mask exactly per reference: allowed = |i-j|<=256 || i<16 || j<16.
// ---------------------------------------------------------------------------
__global__ __launch_bounds__(256, 2) void attn_f32(
    const float* __restrict__ Qp, const float* __restrict__ Kp,
    const float* __restrict__ Vp, const float* __restrict__ amask,
    float* __restrict__ AO)
{
  __shared__ float Qs[32][68], Ks[32][68], Vs[32][68];
  __shared__ float sc[32][33];
  __shared__ float mrow[32], lrow[32], arow_s[32];

  const int tid = threadIdx.x;
  const int qt = blockIdx.x;   // 0..63
  const int h  = blockIdx.y;   // 0..15
  const int b  = blockIdx.z;   // 0..3
  const int i0 = qt * 32;

  const size_t head_off = (size_t)(b * H_ + h) * S_ * DK_;
  const float* Qh = Qp + head_off;
  const float* Kh = Kp + head_off;
  const float* Vh = Vp + head_off;

  // stage Q tile (32x64)
#pragma unroll
  for (int r = 0; r < 2; ++r) {
    const int f = tid + r * 256;           // float4 index, 512 total
    const int row = f >> 4, col = (f & 15) * 4;
    *(float4*)&Qs[row][col] = *(const float4*)(Qh + (size_t)(i0 + row) * DK_ + col);
  }
  if (tid < 32) { mrow[tid] = -1e30f; lrow[tid] = 0.f; }

  float acc[8] = {0.f, 0.f, 0.f, 0.f, 0.f, 0.f, 0.f, 0.f};
  const int qr = tid & 31;    // query row within tile
  const int kg = tid >> 5;    // 0..7: key group (scores) / dim group (PV)

  int start, t_lo, t_hi;
  if (i0 == 0) { start = 0; t_lo = 0; t_hi = 63; }
  else {
    start = -1;                                  // -1 encodes "tile 0 first"
    int lo = (i0 - WIN_) >> 5;
    t_lo = lo < 1 ? 1 : lo;
    int hi = (i0 >> 5) + 8;
    t_hi = hi > 63 ? 63 : hi;
  }

  for (int tt = start; tt <= t_hi; ++tt) {
    if (tt >= 0 && tt < t_lo) continue;
    const int kt = (tt < 0) ? 0 : tt;

    __syncthreads();   // previous tile's PV readers done
    // stage K and V tiles (32x64 each)
#pragma unroll
    for (int r = 0; r < 2; ++r) {
      const int f = tid + r * 256;
      const int row = f >> 4, col = (f & 15) * 4;
      *(float4*)&Ks[row][col] = *(const float4*)(Kh + (size_t)(kt * 32 + row) * DK_ + col);
      *(float4*)&Vs[row][col] = *(const float4*)(Vh + (size_t)(kt * 32 + row) * DK_ + col);
    }
    __syncthreads();

    // scores: thread computes rows qr, keys kg*4 .. kg*4+3
    float s0 = 0.f, s1 = 0.f, s2 = 0.f, s3 = 0.f;
#pragma unroll
    for (int d4 = 0; d4 < 16; ++d4) {
      const float4 qv = *(float4*)&Qs[qr][d4 * 4];
      const float4 k0 = *(float4*)&Ks[kg * 4 + 0][d4 * 4];
      const float4 k1 = *(float4*)&Ks[kg * 4 + 1][d4 * 4];
      const float4 k2 = *(float4*)&Ks[kg * 4 + 2][d4 * 4];
      const float4 k3 = *(float4*)&Ks[kg * 4 + 3][d4 * 4];
      s0 += qv.x*k0.x + qv.y*k0.y + qv.z*k0.z + qv.w*k0.w;
      s1 += qv.x*k1.x + qv.y*k1.y + qv.z*k1.z + qv.w*k1.w;
      s2 += qv.x*k2.x + qv.y*k2.y + qv.z*k2.z + qv.w*k2.w;
      s3 += qv.x*k3.x + qv.y*k3.y + qv.z*k3.z + qv.w*k3.w;
    }
    {
      const int i = i0 + qr;
      float sv[4] = {s0, s1, s2, s3};
#pragma unroll
      for (int u = 0; u < 4; ++u) {
        const int j = kt * 32 + kg * 4 + u;
        const int diff = i - j;
        const bool allowed = (diff <= WIN_ && diff >= -WIN_) || (i < GLB_) || (j < GLB_);
        sc[qr][kg * 4 + u] = allowed ? (sv[u] * 0.125f + amask[b * S_ + j]) : -1e30f;
      }
    }
    __syncthreads();

    // online-softmax row update (32 threads, one per row)
    if (tid < 32) {
      const int r = tid;
      float mt = sc[r][0];
#pragma unroll
      for (int j = 1; j < 32; ++j) mt = fmaxf(mt, sc[r][j]);
      const float mo = mrow[r];
      const float mn = fmaxf(mo, mt);
      const float alpha = __expf(mo - mn);
      float lsum = 0.f;
#pragma unroll
      for (int j = 0; j < 32; ++j) {
        const float p = __expf(sc[r][j] - mn);
        sc[r][j] = p;
        lsum += p;
      }
      lrow[r] = lrow[r] * alpha + lsum;
      mrow[r] = mn;
      arow_s[r] = alpha;
    }
    __syncthreads();

    // PV: thread owns (row qr, dims kg*8 .. kg*8+7)
    const float al = arow_s[qr];
#pragma unroll
    for (int u = 0; u < 8; ++u) acc[u] *= al;
#pragma unroll
    for (int j = 0; j < 32; ++j) {
      const float p = sc[qr][j];
      const float4 v0 = *(float4*)&Vs[j][kg * 8];
      const float4 v1 = *(float4*)&Vs[j][kg * 8 + 4];
      acc[0] = fmaf(p, v0.x, acc[0]); acc[1] = fmaf(p, v0.y, acc[1]);
      acc[2] = fmaf(p, v0.z, acc[2]); acc[3] = fmaf(p, v0.w, acc[3]);
      acc[4] = fmaf(p, v1.x, acc[4]); acc[5] = fmaf(p, v1.y, acc[5]);
      acc[6] = fmaf(p, v1.z, acc[6]); acc[7] = fmaf(p, v1.w, acc[7]);
    }
  }

  __syncthreads();
  const float linv = 1.0f / lrow[qr];
  float* dst = AO + ((size_t)b * S_ + i0 + qr) * D_ + h * DK_ + kg * 8;
  float4 o0 = make_float4(acc[0] * linv, acc[1] * linv, acc[2] * linv, acc[3] * linv);
  float4 o1 = make_float4(acc[4] * linv, acc[5] * linv, acc[6] * linv, acc[7] * linv);
  *(float4*)dst = o0; *(float4*)(dst + 4) = o1;
}

// ---------------------------------------------------------------------------
extern "C" void kernel_launch(void* const* d_in, const int* in_sizes, int n_in,
                              void* d_out, int out_size, void* d_ws, size_t ws_size,
                              hipStream_t stream) {
  const float* q  = (const float*)d_in[0];
  const float* k  = (const float*)d_in[1];
  const float* v  = (const float*)d_in[2];
  const float* am = (const float*)d_in[3];
  const float* wq = (const float*)d_in[4];
  const float* bq = (const float*)d_in[5];
  const float* wk = (const float*)d_in[6];
  const float* bk = (const float*)d_in[7];
  const float* wv = (const float*)d_in[8];
  const float* bv = (const float*)d_in[9];
  const float* wo = (const float*)d_in[10];
  const float* bo = (const float*)d_in[11];
  float* out = (float*)d_out;

  const size_t PER = (size_t)B_ * H_ * S_ * DK_;   // 8,388,608 floats
  float* Qp = (float*)d_ws;
  float* Kp = Qp + PER;
  float* Vp = Kp + PER;
  float* AO = Vp + PER;

  dim3 gg(D_ / BN, (B_ * S_) / BM);                // (8, 64)
  gemm_f32<<<gg, 256, 0, stream>>>(q, wq, bq, Qp, 1);
  gemm_f32<<<gg, 256, 0, stream>>>(k, wk, bk, Kp, 1);
  gemm_f32<<<gg, 256, 0, stream>>>(v, wv, bv, Vp, 1);
  attn_f32<<<dim3(S_ / 32, H_, B_), 256, 0, stream>>>(Qp, Kp, Vp, am, AO);
  gemm_f32<<<gg, 256, 0, stream>>>(AO, wo, bo, out, 0);
}